// Round 4
// baseline (97915.326 us; speedup 1.0000x reference)
//
#include <hip/hip_runtime.h>
#include <stdint.h>

// ---------------------------------------------------------------------------
// Seq2seq LSTM autoencoder (T=4096, H=1024, L=2), fp32 end-to-end.
// Round 4: layer-pipelined scans. 3 kernels:
//   scan2(enc L0+L1 lockstep) -> scan2(dec L0+L1 lockstep) -> projection
// In one scan iteration i, L0 computes h0[i] and L1 computes h1[i-1]; both
// are stored into ONE combined 2048-value slot, so each iteration has a
// single all-to-all poll. 256 blocks x 512 threads (waves 0-3 = L0 gates,
// 4-7 = L1 gates; 4 h-rows/block/layer). Per-thread footprint identical to
// round 3 (128 fp32 weights in VGPRs, ~92 VGPR); __launch_bounds__(512,4)
// caps VGPR at 128 -> 2 blocks/CU -> co-residency needs only 128 of 256 CUs.
// h streams via LLC as fp32 split into two self-validating tagged dwords
// (MAGIC<<16)|half, relaxed agent-scope atomics. Enc/dec reuse one region
// with different magics (kernel boundary orders everything).
// ---------------------------------------------------------------------------

#define T_STEPS 4096
#define H_DIM   1024
#define SLOT_DW 4096              // 2048 fp32 (h0|h1) x 2 tagged dwords
#define NSLOT   4098
#define LSTRIDE ((size_t)4096*1024)
#define M1 0x7E57u
#define M2 0x7E58u
#define PANIC_ITERS (1u<<27)

using u32 = uint32_t;

static __device__ __forceinline__ float sigf(float x){ return 1.0f/(1.0f+__expf(-x)); }
static __device__ __forceinline__ float tanh_f(float x){
  x = fminf(20.f, fmaxf(-20.f, x));
  float e = __expf(-2.f*x);
  return (1.f-e)/(1.f+e);
}

static __device__ __forceinline__ float4 untag4(const u32* q){
  float4 f;
  f.x=__uint_as_float((q[0]&0xFFFFu)|(q[1]<<16));
  f.y=__uint_as_float((q[2]&0xFFFFu)|(q[3]<<16));
  f.z=__uint_as_float((q[4]&0xFFFFu)|(q[5]<<16));
  f.w=__uint_as_float((q[6]&0xFFFFu)|(q[7]<<16));
  return f;
}

// Poll this thread's 8 dwords of a slot until tagged; deposit 4 fp32 into LDS.
static __device__ __forceinline__ void poll_fill(const u32* slot, u32 magic,
                                                 float* st, int wb, int tid,
                                                 u32* panic){
  const u32* q = slot + tid*8;
  u32 v[8]; u32 it=0;
  for(;;){
    #pragma unroll
    for(int m=0;m<8;m++) v[m]=__hip_atomic_load(q+m,__ATOMIC_RELAXED,__HIP_MEMORY_SCOPE_AGENT);
    bool ok = true;
    #pragma unroll
    for(int m=0;m<8;m++) ok = ok && ((v[m]>>16)==magic);
    if(ok) break;
    ++it;
    if((it & 511u)==0u){
      if(__hip_atomic_load(panic,__ATOMIC_RELAXED,__HIP_MEMORY_SCOPE_AGENT)==0xDEADBEEFu) break;
      if(it>PANIC_ITERS){ __hip_atomic_store(panic,0xDEADBEEFu,__ATOMIC_RELAXED,__HIP_MEMORY_SCOPE_AGENT); break; }
    }
    __builtin_amdgcn_s_sleep(1);
  }
  float4 f;
  f.x=__uint_as_float((v[0]&0xFFFFu)|(v[1]<<16));
  f.y=__uint_as_float((v[2]&0xFFFFu)|(v[3]<<16));
  f.z=__uint_as_float((v[4]&0xFFFFu)|(v[5]<<16));
  f.w=__uint_as_float((v[6]&0xFFFFu)|(v[7]<<16));
  *(float4*)(st+wb)=f;
}

static __device__ __forceinline__ void store_h(u32* slot, u32 magic, int e, float h){
  u32 b=__float_as_uint(h);
  __hip_atomic_store(slot+2*e,   (magic<<16)|(b&0xFFFFu), __ATOMIC_RELAXED,__HIP_MEMORY_SCOPE_AGENT);
  __hip_atomic_store(slot+2*e+1, (magic<<16)|(b>>16),     __ATOMIC_RELAXED,__HIP_MEMORY_SCOPE_AGENT);
}

// Two-layer lockstep scan. Iteration i: L0 computes h0[i], L1 computes h1[i-1].
// Slot s: h0[s-1] entries 0..1023, h1[s-2] entries 1024..2047 (tagged pairs).
// Stage LDS elements (padded +4 words/32): x|const 0..1023, h0 1024..2047,
// h1 2048..3071. L0 waves dot elements 0..2047, L1 waves 1024..3071.
// isenc: input = x[i]; writes finals F/fh_out. !isenc: input = fh (const),
// initial state from F/fh.
__global__ __launch_bounds__(512,4) void lstm_scan2(
    const float* __restrict__ xin, const float* __restrict__ fh,
    u32* __restrict__ R, u32 magic,
    const float* __restrict__ Wih, const float* __restrict__ Whh,
    const float* __restrict__ bih, const float* __restrict__ bhh,
    float* __restrict__ F,            // [0..1023]=c0 fin, [1024..2047]=c1 fin,
                                      // [2048..3071]=h0 fin
    float* __restrict__ fh_out,       // enc: final_hidden out; dec: unused
    u32* __restrict__ panic, int isenc)
{
  __shared__ __align__(16) float st[3456];
  __shared__ float gl[32];

  const int tid=threadIdx.x;
  const int w=tid>>6, l=tid&63;
  const int L=w>>2, g=w&3;
  const int hr0=blockIdx.x*4;
  const int grow0=(g<<10)+hr0;
  const int fb  = tid*4 + ((tid>>3)<<2);   // x/const stage word base (tid<256)
  const int wbH = 1152 + fb;               // poll deposit word base (all 512)
  const int sb  = (L ? 1152 : 0) + l*36;   // dot segment word base

  // fp32 weights in VGPRs: 4 rows x 32-col segment of [W_ih | W_hh], own layer
  float wr0[32],wr1[32],wr2[32],wr3[32];
  {
    const float* WI = Wih + (size_t)L*LSTRIDE;
    const float* WH = Whh + (size_t)L*LSTRIDE;
    const float* srcb = (l<32) ? WI + (size_t)grow0*H_DIM + l*32
                               : WH + (size_t)grow0*H_DIM + (l-32)*32;
    #pragma unroll
    for(int i=0;i<8;i++){
      float4 a0=*(const float4*)(srcb + i*4);
      float4 a1=*(const float4*)(srcb + 1024 + i*4);
      float4 a2=*(const float4*)(srcb + 2048 + i*4);
      float4 a3=*(const float4*)(srcb + 3072 + i*4);
      wr0[4*i]=a0.x; wr0[4*i+1]=a0.y; wr0[4*i+2]=a0.z; wr0[4*i+3]=a0.w;
      wr1[4*i]=a1.x; wr1[4*i+1]=a1.y; wr1[4*i+2]=a1.z; wr1[4*i+3]=a1.w;
      wr2[4*i]=a2.x; wr2[4*i+1]=a2.y; wr2[4*i+2]=a2.z; wr2[4*i+3]=a2.w;
      wr3[4*i]=a3.x; wr3[4*i+1]=a3.y; wr3[4*i+2]=a3.z; wr3[4*i+3]=a3.w;
    }
  }

  // tail state (tid<8): layer Lt=tid>>2, row j=tid&3
  float bI=0,bF=0,bG=0,bO=0,c_st=0.f,h_st=0.f;
  const int Lt=tid>>2, j=tid&3, row=hr0+j;
  if(tid<8){
    const float* bi = bih + Lt*4096;
    const float* bh = bhh + Lt*4096;
    bI=bi[row]      + bh[row];
    bF=bi[row+1024] + bh[row+1024];
    bG=bi[row+2048] + bh[row+2048];
    bO=bi[row+3072] + bh[row+3072];
    if(!isenc){
      c_st = F[Lt*1024 + row];
      h_st = Lt ? fh[row] : F[2048 + row];
    }
    store_h(R, magic, Lt*1024 + row, h_st);        // seed slot 0
  }

  for(int i=0;i<=T_STEPS;++i){
    if(isenc){
      if(i<T_STEPS && tid<256){
        float4 xv=*(const float4*)(xin + (size_t)i*H_DIM + tid*4);
        *(float4*)(st+fb)=xv;
      }
    } else if(i==0 && tid<256){                    // constant input, staged once
      float4 xv=*(const float4*)(fh + tid*4);
      *(float4*)(st+fb)=xv;
    }
    poll_fill(R + (size_t)i*SLOT_DW, magic, st, wbH, tid, panic);
    __syncthreads();
    float p0=0.f,p1=0.f,p2=0.f,p3=0.f;
    #pragma unroll
    for(int k=0;k<8;k++){
      float4 s=*(const float4*)(st+sb+k*4);
      p0+=s.x*wr0[4*k]+s.y*wr0[4*k+1]+s.z*wr0[4*k+2]+s.w*wr0[4*k+3];
      p1+=s.x*wr1[4*k]+s.y*wr1[4*k+1]+s.z*wr1[4*k+2]+s.w*wr1[4*k+3];
      p2+=s.x*wr2[4*k]+s.y*wr2[4*k+1]+s.z*wr2[4*k+2]+s.w*wr2[4*k+3];
      p3+=s.x*wr3[4*k]+s.y*wr3[4*k+1]+s.z*wr3[4*k+2]+s.w*wr3[4*k+3];
    }
    #pragma unroll
    for(int off=32;off;off>>=1){
      p0+=__shfl_down(p0,off,64); p1+=__shfl_down(p1,off,64);
      p2+=__shfl_down(p2,off,64); p3+=__shfl_down(p3,off,64);
    }
    if(l==0){ gl[w*4+0]=p0; gl[w*4+1]=p1; gl[w*4+2]=p2; gl[w*4+3]=p3; }
    __syncthreads();
    if(tid<8){
      bool masked = (Lt==1 && i==0) || (Lt==0 && i==T_STEPS);
      if(!masked){
        float gi=bI+gl[Lt*16+j],   gf=bF+gl[Lt*16+4+j];
        float gg=bG+gl[Lt*16+8+j], go=bO+gl[Lt*16+12+j];
        c_st = sigf(gf)*c_st + sigf(gi)*tanh_f(gg);
        h_st = sigf(go)*tanh_f(c_st);
      }
      store_h(R + (size_t)(i+1)*SLOT_DW, magic, Lt*1024 + row, h_st);
      if(isenc){
        if(Lt==0 && i==T_STEPS-1){ F[row]=c_st; F[2048+row]=h_st; }
        if(Lt==1 && i==T_STEPS)  { F[1024+row]=c_st; fh_out[row]=h_st; }
      }
    }
    __syncthreads();
  }
}

// out[(4095-tp), o] = leaky( sum_k oW[o,k] * h1d[tp][k] + ob[o] )
// h1d[tp] = slot (tp+2) upper half (dwords 2048..4095).
__global__ __launch_bounds__(256) void proj_out(
    const u32* __restrict__ R, const float* __restrict__ oW,
    const float* __restrict__ ob, float* __restrict__ out)
{
  __shared__ __align__(16) float hb[1024];
  const int tp=blockIdx.x, tid=threadIdx.x;
  float4 f = untag4(R + (size_t)(tp+2)*SLOT_DW + 2048 + tid*8);
  *(float4*)(hb + tid*4)=f;
  __syncthreads();
  #pragma unroll
  for(int jj=0;jj<4;jj++){
    int o = tid + 256*jj;
    const float* wr = oW + (size_t)o*H_DIM;
    float acc=0.f;
    for(int k=0;k<1024;k+=4){
      float4 wv=*(const float4*)(wr+k);
      acc += wv.x*hb[k]+wv.y*hb[k+1]+wv.z*hb[k+2]+wv.w*hb[k+3];
    }
    acc += ob[o];
    acc = acc>0.f ? acc : 0.01f*acc;
    out[(size_t)(4095-tp)*H_DIM + o]=acc;
  }
}

extern "C" void kernel_launch(void* const* d_in, const int* in_sizes, int n_in,
                              void* d_out, int out_size, void* d_ws, size_t ws_size,
                              hipStream_t stream) {
  const float* x    = (const float*)d_in[0];
  const float* eWih = (const float*)d_in[1];
  const float* eWhh = (const float*)d_in[2];
  const float* ebih = (const float*)d_in[3];
  const float* ebhh = (const float*)d_in[4];
  const float* dWih = (const float*)d_in[5];
  const float* dWhh = (const float*)d_in[6];
  const float* dbih = (const float*)d_in[7];
  const float* dbhh = (const float*)d_in[8];
  const float* oW   = (const float*)d_in[9];
  const float* ob   = (const float*)d_in[10];
  float* out = (float*)d_out;
  u32* ws = (u32*)d_ws;

  const size_t REGION = (size_t)NSLOT*SLOT_DW;   // dwords
  u32*   R     = ws;
  float* F     = (float*)(ws + REGION);          // 3072 floats: c0,c1,h0 finals
  u32*   panic = ws + REGION + 3072;
  float* fh    = out + (size_t)T_STEPS*H_DIM;    // final_hidden (written by enc)

  // clear tags + finals + panic (stale tags / 0xAA poison must not match MAGIC)
  hipMemsetAsync(d_ws, 0, (REGION + 3072 + 64)*4, stream);

  // encoder: L0+L1 lockstep, magic M1; writes F and final_hidden
  lstm_scan2<<<256,512,0,stream>>>(x, nullptr, R, M1,
      eWih, eWhh, ebih, ebhh, F, fh, panic, 1);
  // decoder: L0+L1 lockstep, magic M2 (region reuse safe across boundary);
  // const input = final_hidden, initial state from F/fh
  lstm_scan2<<<256,512,0,stream>>>(nullptr, fh, R, M2,
      dWih, dWhh, dbih, dbhh, F, nullptr, panic, 0);
  // projection + leaky ReLU + flip
  proj_out<<<4096,256,0,stream>>>(R, oW, ob, out);
}